// Round 1
// baseline (17780.859 us; speedup 1.0000x reference)
//
#include <hip/hip_runtime.h>
#include <cstdint>
#include <cstddef>

// SimpleRNN on MI355X: 2-stage pipelined persistent RNN.
//   h1_t = tanh(x_t Wih0^T + h2_{t-1} Whh0^T + bc0)      (L0 workgroups)
//   h2_t = tanh(h1_t (Wih1+Whh1)^T + b1c)                 (L1 workgroups)
//   y_t  = h2_t Wout^T + bout                             (folded into L0 at t+1)
// 8 batch-groups of 16; per group 16 column-WGs per stage; 256 WGs total (1/CU).
// Weights live in per-wave VGPRs (f16 MFMA B-fragments); h handoff through small
// global ring buffers with agent-scope release/acquire counters.

typedef _Float16 f16;
typedef _Float16 f16x8 __attribute__((ext_vector_type(8)));
typedef float    f32x4 __attribute__((ext_vector_type(4)));

#define NB 128
#define NT 1024
#define NI 256
#define NH 512
#define NO 256
#define RDEPTH 4

// ws byte offsets (total use ~3.2 MB)
#define WS_WHH0   (size_t)(0)         // 512*512 f16
#define WS_W1C    (size_t)(524288)    // 512*512 f16  (Wih1+Whh1)
#define WS_WOUT   (size_t)(1048576)   // 256*512 f16
#define WS_WIH0   (size_t)(1310720)   // 512*256 f16
#define WS_BC0    (size_t)(1572864)   // 512 f32 (b_ih0+b_hh0)
#define WS_B1C    (size_t)(1574912)   // 512 f32 (b_ih1+b_hh1)
#define WS_BOUT   (size_t)(1576960)   // 256 f32
#define WS_H1RING (size_t)(2097152)   // [8][4][16][512] f16
#define WS_H2RING (size_t)(2621440)   // [8][4][16][512] f16
#define WS_CNT    (size_t)(3145728)   // h1cnt: 8 @128B stride; h2cnt at +1024

__device__ __forceinline__ f32x4 mfma16(f16x8 a, f16x8 b, f32x4 c) {
  return __builtin_amdgcn_mfma_f32_16x16x32_f16(a, b, c, 0, 0, 0);
}

// Poll a monotonically increasing counter until >= target (agent scope).
__device__ __forceinline__ void poll_ge(int* p, int target) {
  while (__hip_atomic_load(p, __ATOMIC_RELAXED, __HIP_MEMORY_SCOPE_AGENT) < target)
    __builtin_amdgcn_s_sleep(1);
  (void)__hip_atomic_load(p, __ATOMIC_ACQUIRE, __HIP_MEMORY_SCOPE_AGENT);
}

// Copy one 16x512 f16 panel global -> LDS with +8 f16 row padding (bank-conflict free).
__device__ __forceinline__ void stage_copy(f16* dst, const f16* __restrict__ src, int tid) {
  const int row = tid >> 4, seg = tid & 15;                 // 256 threads: 64 B each
  const f32x4* s4 = (const f32x4*)(src + row * 512 + seg * 32);
  f32x4* d4 = (f32x4*)(dst + row * 520 + seg * 32);
  d4[0] = s4[0]; d4[1] = s4[1]; d4[2] = s4[2]; d4[3] = s4[3];
}

__global__ __launch_bounds__(256) void rnn9277_prep(
    const float* __restrict__ h0,
    const float* __restrict__ Wih0, const float* __restrict__ bih0,
    const float* __restrict__ Whh0, const float* __restrict__ bhh0,
    const float* __restrict__ Wih1, const float* __restrict__ bih1,
    const float* __restrict__ Whh1, const float* __restrict__ bhh1,
    const float* __restrict__ Woutp, const float* __restrict__ boutp,
    char* __restrict__ ws)
{
  const int tid = blockIdx.x * 256 + threadIdx.x;
  const int stride = gridDim.x * 256;
  f16* whh0 = (f16*)(ws + WS_WHH0);
  f16* w1c  = (f16*)(ws + WS_W1C);
  f16* wout = (f16*)(ws + WS_WOUT);
  f16* wih0 = (f16*)(ws + WS_WIH0);
  float* bc0 = (float*)(ws + WS_BC0);
  float* b1c = (float*)(ws + WS_B1C);
  float* bo  = (float*)(ws + WS_BOUT);
  f16* h2ring = (f16*)(ws + WS_H2RING);
  int* h1cnt = (int*)(ws + WS_CNT);
  int* h2cnt = (int*)(ws + WS_CNT + 1024);

  for (int i = tid; i < NH * NH; i += stride) whh0[i] = (f16)Whh0[i];
  for (int i = tid; i < NH * NH; i += stride) w1c[i]  = (f16)(Wih1[i] + Whh1[i]);
  for (int i = tid; i < NO * NH; i += stride) wout[i] = (f16)Woutp[i];
  for (int i = tid; i < NH * NI; i += stride) wih0[i] = (f16)Wih0[i];
  for (int i = tid; i < NH; i += stride) { bc0[i] = bih0[i] + bhh0[i]; b1c[i] = bih1[i] + bhh1[i]; }
  for (int i = tid; i < NO; i += stride) bo[i] = boutp[i];
  // h0 -> h2 ring slot 3 (t = -1)
  for (int i = tid; i < NB * NH; i += stride) {
    int b = i >> 9, c = i & 511;
    int g = b >> 4, bl = b & 15;
    h2ring[((size_t)(g * RDEPTH + 3) * 16 + bl) * 512 + c] = (f16)h0[i];
  }
  if (tid < 8) { h1cnt[tid * 32] = 0; h2cnt[tid * 32] = 16; }
}

__global__ __launch_bounds__(256) void rnn9277_chain(
    const float* __restrict__ x, float* __restrict__ out, char* __restrict__ ws)
{
  const int wg = blockIdx.x;
  const int tid = threadIdx.x;
  const int wave = tid >> 6, lane = tid & 63;
  const int row16 = lane & 15, kq = lane >> 4;
  const bool isL0 = wg < 128;
  const int g = (wg & 127) >> 4, j = wg & 15;

  const f16* whh0 = (const f16*)(ws + WS_WHH0);
  const f16* w1c  = (const f16*)(ws + WS_W1C);
  const f16* wout = (const f16*)(ws + WS_WOUT);
  const f16* wih0 = (const f16*)(ws + WS_WIH0);
  const float* bc0 = (const float*)(ws + WS_BC0);
  const float* b1c = (const float*)(ws + WS_B1C);
  const float* bo  = (const float*)(ws + WS_BOUT);
  f16* h1ring = (f16*)(ws + WS_H1RING);
  f16* h2ring = (f16*)(ws + WS_H2RING);
  int* h1cnt = (int*)(ws + WS_CNT);
  int* h2cnt = (int*)(ws + WS_CNT + 1024);

  __shared__ __align__(16) f16 stage[2][16 * 520];   // double-buffered h panel

  // ---- Preload resident weight fragments (per wave role) ----
  f16x8 Bm[16];   // waves 0/1: Whh0 or W1c cols; L0 wave2: Wout cols
  f16x8 Bx[8];    // L0 waves 0/1: Wih0 cols
  float bias0 = 0.f;
  if (isL0) {
    if (wave < 2) {
      const int col = j * 32 + wave * 16 + row16;
      const f16* p = whh0 + (size_t)col * NH + kq * 8;
      #pragma unroll
      for (int kk = 0; kk < 16; kk++) Bm[kk] = *(const f16x8*)(p + kk * 32);
      const f16* q = wih0 + (size_t)col * NI + kq * 8;
      #pragma unroll
      for (int kk = 0; kk < 8; kk++) Bx[kk] = *(const f16x8*)(q + kk * 32);
      bias0 = bc0[col];
    } else if (wave == 2) {
      const f16* p = wout + (size_t)(j * 16 + row16) * NH + kq * 8;
      #pragma unroll
      for (int kk = 0; kk < 16; kk++) Bm[kk] = *(const f16x8*)(p + kk * 32);
      bias0 = bo[j * 16 + row16];
    }
  } else {
    if (wave < 2) {
      const int col = j * 32 + wave * 16 + row16;
      const f16* p = w1c + (size_t)col * NH + kq * 8;
      #pragma unroll
      for (int kk = 0; kk < 16; kk++) Bm[kk] = *(const f16x8*)(p + kk * 32);
      bias0 = b1c[col];
    }
  }

  if (isL0) {
    // ================= Layer-0 (+ output head) workgroups =================
    const float* xg = x + (size_t)(g * 16) * NT * NI;  // this group's batch rows
    for (int t = 0; t <= NT; ++t) {
      // x-part of layer0: independent of the recurrence -> compute before poll.
      f32x4 acc = {0.f, 0.f, 0.f, 0.f};
      if (t < NT && wave < 2) {
        const float* xp = xg + (size_t)row16 * (NT * NI) + (size_t)t * NI + kq * 8;
        #pragma unroll
        for (int kk = 0; kk < 8; kk++) {
          f32x4 lo = *(const f32x4*)(xp + kk * 32);
          f32x4 hi = *(const f32x4*)(xp + kk * 32 + 4);
          f16x8 a;
          a[0] = (f16)lo[0]; a[1] = (f16)lo[1]; a[2] = (f16)lo[2]; a[3] = (f16)lo[3];
          a[4] = (f16)hi[0]; a[5] = (f16)hi[1]; a[6] = (f16)hi[2]; a[7] = (f16)hi[3];
          acc = mfma16(a, Bx[kk], acc);
        }
      }
      // Wait for h2[t-1] (16 L1 slice-writes per step; +16 initial from prep).
      poll_ge(&h2cnt[g * 32], 16 + 16 * t);
      f16* st = stage[t & 1];
      stage_copy(st, h2ring + (size_t)(g * RDEPTH + ((t + 3) & 3)) * (16 * 512), tid);
      __syncthreads();

      const f16* ap = st + row16 * 520 + kq * 8;
      if (wave == 2) {
        if (t > 0) {  // y_{t-1} = h2_{t-1} Wout^T + bout
          f32x4 accy = {0.f, 0.f, 0.f, 0.f};
          #pragma unroll
          for (int kk = 0; kk < 16; kk++)
            accy = mfma16(*(const f16x8*)(ap + kk * 32), Bm[kk], accy);
          const int ocol = j * 16 + row16;
          #pragma unroll
          for (int r = 0; r < 4; r++) {
            const int b = g * 16 + kq * 4 + r;
            out[((size_t)b * NT + (t - 1)) * NO + ocol] = accy[r] + bias0;
          }
        }
      } else if (wave < 2 && t < NT) {
        #pragma unroll
        for (int kk = 0; kk < 16; kk++)
          acc = mfma16(*(const f16x8*)(ap + kk * 32), Bm[kk], acc);
        const int col = j * 32 + wave * 16 + row16;
        f16* dst = h1ring + (size_t)(g * RDEPTH + (t & 3)) * (16 * 512) + col;
        #pragma unroll
        for (int r = 0; r < 4; r++)
          dst[(kq * 4 + r) * 512] = (f16)tanhf(acc[r] + bias0);
      }
      __syncthreads();  // drains each wave's global stores (waitcnt before barrier)
      if (t < NT && tid == 0)
        __hip_atomic_fetch_add(&h1cnt[g * 32], 1, __ATOMIC_RELEASE, __HIP_MEMORY_SCOPE_AGENT);
    }
  } else {
    // ================= Layer-1 workgroups =================
    for (int t = 0; t < NT; ++t) {
      poll_ge(&h1cnt[g * 32], 16 * (t + 1));
      f16* st = stage[t & 1];
      stage_copy(st, h1ring + (size_t)(g * RDEPTH + (t & 3)) * (16 * 512), tid);
      __syncthreads();

      if (wave < 2) {
        const f16* ap = st + row16 * 520 + kq * 8;
        f32x4 acc = {0.f, 0.f, 0.f, 0.f};
        #pragma unroll
        for (int kk = 0; kk < 16; kk++)
          acc = mfma16(*(const f16x8*)(ap + kk * 32), Bm[kk], acc);
        const int col = j * 32 + wave * 16 + row16;
        f16* dst = h2ring + (size_t)(g * RDEPTH + (t & 3)) * (16 * 512) + col;
        #pragma unroll
        for (int r = 0; r < 4; r++)
          dst[(kq * 4 + r) * 512] = (f16)tanhf(acc[r] + bias0);
      }
      __syncthreads();
      if (tid == 0)
        __hip_atomic_fetch_add(&h2cnt[g * 32], 1, __ATOMIC_RELEASE, __HIP_MEMORY_SCOPE_AGENT);
    }
  }
}

extern "C" void kernel_launch(void* const* d_in, const int* in_sizes, int n_in,
                              void* d_out, int out_size, void* d_ws, size_t ws_size,
                              hipStream_t stream) {
  const float* x    = (const float*)d_in[0];
  const float* h0   = (const float*)d_in[1];
  const float* Wih0 = (const float*)d_in[2];
  const float* bih0 = (const float*)d_in[3];
  const float* Whh0 = (const float*)d_in[4];
  const float* bhh0 = (const float*)d_in[5];
  const float* Wih1 = (const float*)d_in[6];
  const float* bih1 = (const float*)d_in[7];
  const float* Whh1 = (const float*)d_in[8];
  const float* bhh1 = (const float*)d_in[9];
  const float* Wout = (const float*)d_in[10];
  const float* bout = (const float*)d_in[11];
  char* ws = (char*)d_ws;
  float* out = (float*)d_out;

  rnn9277_prep<<<dim3(128), dim3(256), 0, stream>>>(
      h0, Wih0, bih0, Whh0, bhh0, Wih1, bih1, Whh1, bhh1, Wout, bout, ws);
  rnn9277_chain<<<dim3(256), dim3(256), 0, stream>>>(x, out, ws);
}

// Round 2
// 6271.438 us; speedup vs baseline: 2.8352x; 2.8352x over previous
//
#include <hip/hip_runtime.h>
#include <cstdint>
#include <cstddef>

// SimpleRNN on MI355X — round 2: cheap cross-XCD handoff protocol.
//   h1_t = tanh(x_t Wih0^T + h2_{t-1} Whh0^T + bc0)      (L0 WGs)
//   h2_t = tanh(h1_t (Wih1+Whh1)^T + b1c)                 (L1 WGs)
//   y_t  = h2_t Wout^T + bout                             (L0 WGs, off critical path)
// 8 batch-groups of 16 rows; per group: 4 L0-WGs + 4 L1-WGs, 512 threads each.
// All ring/flag traffic = relaxed agent-scope atomics (sc1, bypass per-XCD L2):
// no buffer_wbl2 / buffer_inv, no atomic RMW. Producer: sc1 data stores ->
// __syncthreads (drains vmcnt) -> per-WG sc1 flag store. Consumer: wave0 polls
// 4 flags -> barrier -> sc1 ring loads.

typedef _Float16 f16;
typedef _Float16 f16x8 __attribute__((ext_vector_type(8)));
typedef float    f32x4 __attribute__((ext_vector_type(4)));

#define NB 128
#define NT 1024
#define NI 256
#define NH 512
#define NO 256
#define RD 4

#define WS_WHH0 (size_t)(0)        // 512*512 f16
#define WS_W1C  (size_t)(524288)   // 512*512 f16 (Wih1+Whh1)
#define WS_WOUT (size_t)(1048576)  // 256*512 f16
#define WS_WIH0 (size_t)(1310720)  // 512*256 f16
#define WS_BC0  (size_t)(1572864)  // 512 f32
#define WS_B1C  (size_t)(1574912)  // 512 f32
#define WS_BOUT (size_t)(1576960)  // 256 f32
#define WS_H1R  (size_t)(2097152)  // [8][4][16][512] f16
#define WS_H2R  (size_t)(2621440)  // [8][4][16][512] f16
#define WS_FLG  (size_t)(3145728)  // h1 flags 32@64B; h2 flags at +2048

#define AGENT __HIP_MEMORY_SCOPE_AGENT

__device__ __forceinline__ f32x4 mfma16(f16x8 a, f16x8 b, f32x4 c) {
  return __builtin_amdgcn_mfma_f32_16x16x32_f16(a, b, c, 0, 0, 0);
}

__device__ __forceinline__ float fast_tanh(float v) {
  float a = __builtin_fabsf(v);
  float e = __expf(-2.0f * a);                       // v_exp_f32
  float r = (1.0f - e) * __builtin_amdgcn_rcpf(1.0f + e);
  return v < 0.0f ? -r : r;
}

// Poll 4 per-WG flags (64B apart) until all >= target. Relaxed sc1 loads only.
__device__ __forceinline__ void poll4(int* base, int target) {
  for (;;) {
    int a = __hip_atomic_load(base,      __ATOMIC_RELAXED, AGENT);
    int b = __hip_atomic_load(base + 16, __ATOMIC_RELAXED, AGENT);
    int c = __hip_atomic_load(base + 32, __ATOMIC_RELAXED, AGENT);
    int d = __hip_atomic_load(base + 48, __ATOMIC_RELAXED, AGENT);
    if (a >= target && b >= target && c >= target && d >= target) return;
    __builtin_amdgcn_s_sleep(2);
  }
}

__global__ __launch_bounds__(256) void rnn9277_prep(
    const float* __restrict__ h0,
    const float* __restrict__ Wih0, const float* __restrict__ bih0,
    const float* __restrict__ Whh0, const float* __restrict__ bhh0,
    const float* __restrict__ Wih1, const float* __restrict__ bih1,
    const float* __restrict__ Whh1, const float* __restrict__ bhh1,
    const float* __restrict__ Woutp, const float* __restrict__ boutp,
    char* __restrict__ ws)
{
  const int tid = blockIdx.x * 256 + threadIdx.x;
  const int stride = gridDim.x * 256;
  f16* whh0 = (f16*)(ws + WS_WHH0);
  f16* w1c  = (f16*)(ws + WS_W1C);
  f16* wout = (f16*)(ws + WS_WOUT);
  f16* wih0 = (f16*)(ws + WS_WIH0);
  float* bc0 = (float*)(ws + WS_BC0);
  float* b1c = (float*)(ws + WS_B1C);
  float* bo  = (float*)(ws + WS_BOUT);
  uint64_t* h2r64 = (uint64_t*)(ws + WS_H2R);
  int* h1f = (int*)(ws + WS_FLG);
  int* h2f = (int*)(ws + WS_FLG + 2048);

  for (int i = tid; i < NH * NH; i += stride) whh0[i] = (f16)Whh0[i];
  for (int i = tid; i < NH * NH; i += stride) w1c[i]  = (f16)(Wih1[i] + Whh1[i]);
  for (int i = tid; i < NO * NH; i += stride) wout[i] = (f16)Woutp[i];
  for (int i = tid; i < NH * NI; i += stride) wih0[i] = (f16)Wih0[i];
  for (int i = tid; i < NH; i += stride) { bc0[i] = bih0[i] + bhh0[i]; b1c[i] = bih1[i] + bhh1[i]; }
  for (int i = tid; i < NO; i += stride) bo[i] = boutp[i];
  // h0 -> h2 ring slot 3 (t = -1), sc1 8B stores (visible to sc1 readers).
  for (int c = tid; c < NB * NH / 4; c += stride) {
    int b = c >> 7, c4 = c & 127;
    int g = b >> 4, bl = b & 15;
    const float* hp = h0 + (size_t)b * NH + c4 * 4;
    union { uint64_t u; f16 h[4]; } uv;
    uv.h[0] = (f16)hp[0]; uv.h[1] = (f16)hp[1]; uv.h[2] = (f16)hp[2]; uv.h[3] = (f16)hp[3];
    __hip_atomic_store(h2r64 + (size_t)(g * RD + 3) * 2048 + bl * 128 + c4, uv.u,
                       __ATOMIC_RELAXED, AGENT);
  }
  if (tid < 32) {
    __hip_atomic_store(h1f + tid * 16, 0, __ATOMIC_RELAXED, AGENT);
    __hip_atomic_store(h2f + tid * 16, 0, __ATOMIC_RELAXED, AGENT);
  }
}

__global__ __launch_bounds__(512) void rnn9277_chain(
    const float* __restrict__ x, float* __restrict__ out, char* __restrict__ ws)
{
  const int wg = blockIdx.x;                 // 0..63
  const bool isL0 = wg < 32;
  const int g = (wg & 31) >> 2, j = wg & 3;  // group, column-WG
  const int tid = threadIdx.x;               // 0..511
  const int wave = tid >> 6, lane = tid & 63;
  const int row16 = lane & 15, kq = lane >> 4;

  const f16* whh0 = (const f16*)(ws + WS_WHH0);
  const f16* w1c  = (const f16*)(ws + WS_W1C);
  const f16* wout = (const f16*)(ws + WS_WOUT);
  const f16* wih0 = (const f16*)(ws + WS_WIH0);
  const float* bc0 = (const float*)(ws + WS_BC0);
  const float* b1c = (const float*)(ws + WS_B1C);
  const float* bo  = (const float*)(ws + WS_BOUT);
  uint64_t* h1r64 = (uint64_t*)(ws + WS_H1R);
  uint64_t* h2r64 = (uint64_t*)(ws + WS_H2R);
  int* h1fb = (int*)(ws + WS_FLG) + g * 64;          // 4 flags, 64B apart
  int* h2fb = (int*)(ws + WS_FLG + 2048) + g * 64;

  __shared__ __align__(16) f16 stage[2][16 * 520];   // staged h panel (padded)
  __shared__ __align__(16) f16 xpose[16 * 136];      // C-layout -> row-major

  // ---- Resident weight fragments ----
  f16x8 Bh[16];           // Whh0 (L0) or W1c (L1), 16 cols/wave
  f16x8 Bx[8];            // Wih0 (L0)
  f16x8 By[16];           // Wout (L0, waves 0..3)
  float bias = 0.f, ybias = 0.f;
  {
    const int col = j * 128 + wave * 16 + row16;
    const f16* wp = (isL0 ? whh0 : w1c) + (size_t)col * NH + kq * 8;
    #pragma unroll
    for (int kk = 0; kk < 16; kk++) Bh[kk] = *(const f16x8*)(wp + kk * 32);
    bias = (isL0 ? bc0 : b1c)[col];
    if (isL0) {
      const f16* qp = wih0 + (size_t)col * NI + kq * 8;
      #pragma unroll
      for (int kk = 0; kk < 8; kk++) Bx[kk] = *(const f16x8*)(qp + kk * 32);
      if (wave < 4) {
        const int oc = j * 64 + wave * 16 + row16;
        const f16* rp = wout + (size_t)oc * NH + kq * 8;
        #pragma unroll
        for (int kk = 0; kk < 16; kk++) By[kk] = *(const f16x8*)(rp + kk * 32);
        ybias = bo[oc];
      }
    }
  }

  if (isL0) {
    // ================= Layer-0 + output head =================
    for (int t = 0; t <= NT; ++t) {
      // x-part (recurrence-independent, before poll)
      f32x4 acc = {0.f, 0.f, 0.f, 0.f};
      if (t < NT) {
        const float* xp = x + ((size_t)(g * 16 + row16) * NT + t) * NI + kq * 8;
        #pragma unroll
        for (int kk = 0; kk < 8; kk++) {
          f32x4 lo = *(const f32x4*)(xp + kk * 32);
          f32x4 hi = *(const f32x4*)(xp + kk * 32 + 4);
          f16x8 a;
          a[0] = (f16)lo[0]; a[1] = (f16)lo[1]; a[2] = (f16)lo[2]; a[3] = (f16)lo[3];
          a[4] = (f16)hi[0]; a[5] = (f16)hi[1]; a[6] = (f16)hi[2]; a[7] = (f16)hi[3];
          acc = mfma16(a, Bx[kk], acc);
        }
      }
      // wait for h2_{t-1}
      if (tid < 64) poll4(h2fb, t);
      __syncthreads();
      // stage h2_{t-1} (sc1 loads -> LDS, coalesced 8B/thread)
      const uint64_t* rs = h2r64 + (size_t)(g * RD + ((t + 3) & 3)) * 2048;
      f16* st = &stage[t & 1][0];
      #pragma unroll
      for (int i = 0; i < 4; ++i) {
        int c = tid + i * 512;
        int r = c >> 7, c4 = c & 127;
        uint64_t v = __hip_atomic_load(rs + c, __ATOMIC_RELAXED, AGENT);
        *(uint64_t*)(st + r * 520 + c4 * 4) = v;
      }
      __syncthreads();

      const f16* ap = st + row16 * 520 + kq * 8;
      if (t < NT) {
        #pragma unroll
        for (int kk = 0; kk < 16; kk++)
          acc = mfma16(*(const f16x8*)(ap + kk * 32), Bh[kk], acc);
        const int cl = wave * 16 + row16;
        #pragma unroll
        for (int rr = 0; rr < 4; rr++)
          xpose[(kq * 4 + rr) * 136 + cl] = (f16)fast_tanh(acc[rr] + bias);
        __syncthreads();
        // ring store: 8B/thread, coalesced, sc1
        {
          int r = tid >> 5, c4 = tid & 31;
          uint64_t v = *(const uint64_t*)(xpose + r * 136 + c4 * 4);
          __hip_atomic_store(h1r64 + (size_t)(g * RD + (t & 3)) * 2048 + r * 128 + j * 32 + c4,
                             v, __ATOMIC_RELAXED, AGENT);
        }
        __syncthreads();  // drains each wave's sc1 stores (vmcnt before barrier)
        if (tid == 0)
          __hip_atomic_store(h1fb + j * 16, t + 1, __ATOMIC_RELAXED, AGENT);
      }
      // y_{t-1} = h2_{t-1} Wout^T + bout  (off critical path, after flag)
      if (t > 0 && wave < 4) {
        f32x4 ya = {0.f, 0.f, 0.f, 0.f};
        #pragma unroll
        for (int kk = 0; kk < 16; kk++)
          ya = mfma16(*(const f16x8*)(ap + kk * 32), By[kk], ya);
        const int oc = j * 64 + wave * 16 + row16;
        #pragma unroll
        for (int rr = 0; rr < 4; rr++)
          out[((size_t)(g * 16 + kq * 4 + rr) * NT + (t - 1)) * NO + oc] = ya[rr] + ybias;
      }
    }
  } else {
    // ================= Layer-1 =================
    for (int t = 0; t < NT; ++t) {
      if (tid < 64) poll4(h1fb, t + 1);
      __syncthreads();
      const uint64_t* rs = h1r64 + (size_t)(g * RD + (t & 3)) * 2048;
      f16* st = &stage[t & 1][0];
      #pragma unroll
      for (int i = 0; i < 4; ++i) {
        int c = tid + i * 512;
        int r = c >> 7, c4 = c & 127;
        uint64_t v = __hip_atomic_load(rs + c, __ATOMIC_RELAXED, AGENT);
        *(uint64_t*)(st + r * 520 + c4 * 4) = v;
      }
      __syncthreads();

      const f16* ap = st + row16 * 520 + kq * 8;
      f32x4 acc = {0.f, 0.f, 0.f, 0.f};
      #pragma unroll
      for (int kk = 0; kk < 16; kk++)
        acc = mfma16(*(const f16x8*)(ap + kk * 32), Bh[kk], acc);
      const int cl = wave * 16 + row16;
      #pragma unroll
      for (int rr = 0; rr < 4; rr++)
        xpose[(kq * 4 + rr) * 136 + cl] = (f16)fast_tanh(acc[rr] + bias);
      __syncthreads();
      {
        int r = tid >> 5, c4 = tid & 31;
        uint64_t v = *(const uint64_t*)(xpose + r * 136 + c4 * 4);
        __hip_atomic_store(h2r64 + (size_t)(g * RD + (t & 3)) * 2048 + r * 128 + j * 32 + c4,
                           v, __ATOMIC_RELAXED, AGENT);
      }
      __syncthreads();
      if (tid == 0)
        __hip_atomic_store(h2fb + j * 16, t + 1, __ATOMIC_RELAXED, AGENT);
    }
  }
}

extern "C" void kernel_launch(void* const* d_in, const int* in_sizes, int n_in,
                              void* d_out, int out_size, void* d_ws, size_t ws_size,
                              hipStream_t stream) {
  const float* x    = (const float*)d_in[0];
  const float* h0   = (const float*)d_in[1];
  const float* Wih0 = (const float*)d_in[2];
  const float* bih0 = (const float*)d_in[3];
  const float* Whh0 = (const float*)d_in[4];
  const float* bhh0 = (const float*)d_in[5];
  const float* Wih1 = (const float*)d_in[6];
  const float* bih1 = (const float*)d_in[7];
  const float* Whh1 = (const float*)d_in[8];
  const float* bhh1 = (const float*)d_in[9];
  const float* Wout = (const float*)d_in[10];
  const float* bout = (const float*)d_in[11];
  char* ws = (char*)d_ws;
  float* out = (float*)d_out;

  rnn9277_prep<<<dim3(128), dim3(256), 0, stream>>>(
      h0, Wih0, bih0, Whh0, bhh0, Wih1, bih1, Whh1, bhh1, Wout, bout, ws);
  rnn9277_chain<<<dim3(64), dim3(512), 0, stream>>>(x, out, ws);
}